// Round 3
// baseline (241.695 us; speedup 1.0000x reference)
//
#include <hip/hip_runtime.h>
#include <hip/hip_bf16.h>

#define N_NODES 50000
#define N_EDGES 800000
#define MT_TILES 3125   // 50000 / 16

#define NBLK_SORT 400
#define CHUNK_SORT 2000   // NBLK_SORT * CHUNK_SORT == N_EDGES
#define NBKT 196          // ceil(50000 / 256)

typedef __attribute__((ext_vector_type(8))) short frag_ab;   // 8 bf16 (4 VGPRs)
typedef __attribute__((ext_vector_type(4))) float frag_cd;   // 4 fp32 acc

static __device__ __forceinline__ unsigned short f2b(float f) {
    union { float f; unsigned u; } v; v.f = f;
    unsigned r = v.u + 0x7fffu + ((v.u >> 16) & 1u);  // RNE
    return (unsigned short)(r >> 16);
}
static __device__ __forceinline__ float b2f(unsigned short b) {
    union { float f; unsigned u; } v; v.u = ((unsigned)b) << 16;
    return v.f;
}
static __device__ __forceinline__ float blo(unsigned p) { return b2f((unsigned short)(p & 0xffffu)); }
static __device__ __forceinline__ float bhi(unsigned p) { return b2f((unsigned short)(p >> 16)); }

// ---------------- fused prep (cvt x, pack weights) + p1 bucket histogram ----------------
static __device__ __forceinline__ unsigned short packBK_elem(const float* __restrict__ Wa,
                                                             const float* __restrict__ Wb,
                                                             int Ka, int N, int idx) {
    int j = idx & 7;
    int lane = (idx >> 3) & 63;
    int rest = idx >> 9;
    int ntiles = N >> 4;
    int nt = rest % ntiles;
    int kt = rest / ntiles;
    int kk = kt * 32 + (lane >> 4) * 8 + j;
    int nn = nt * 16 + (lane & 15);
    float v = (kk < Ka) ? Wa[kk * N + nn] : Wb[(kk - Ka) * N + nn];
    return f2b(v);
}
static __device__ __forceinline__ unsigned short packBN_elem(const float* __restrict__ Wa,
                                                             const float* __restrict__ Wb,
                                                             int Na, int N, int idx) {
    int j = idx & 7;
    int lane = (idx >> 3) & 63;
    int rest = idx >> 9;
    int ntiles = N >> 4;
    int nt = rest % ntiles;
    int kt = rest / ntiles;
    int kk = kt * 32 + (lane >> 4) * 8 + j;
    int nn = nt * 16 + (lane & 15);
    float v = (nn < Na) ? Wa[kk * Na + nn] : Wb[kk * (N - Na) + (nn - Na)];
    return f2b(v);
}

#define PREP_S0 800000                 // cvt: ushort4 items (N_NODES*64/4)
#define PREP_S1 (PREP_S0 + 32768)      // B1p  128x256
#define PREP_S2 (PREP_S1 + 65536)      // B2p  256x256
#define PREP_S3 (PREP_S2 + 8192)      // Bl1p 128x64
#define PREP_S4 (PREP_S3 + 2048)      // Bl2p 64x32   -> total 908544 = 3549*256
#define PREP_BLKS 3549

__global__ __launch_bounds__(256) void prep_p1_kernel(const float4* __restrict__ x4,
                                                      ushort4* __restrict__ xb4,
                                                      const float* __restrict__ W1s,
                                                      const float* __restrict__ W1n,
                                                      const float* __restrict__ W2s,
                                                      const float* __restrict__ W2n,
                                                      const float* __restrict__ Wl1,
                                                      const float* __restrict__ Wl2,
                                                      unsigned short* __restrict__ B1p,
                                                      unsigned short* __restrict__ B2p,
                                                      unsigned short* __restrict__ Bl1p,
                                                      unsigned short* __restrict__ Bl2p,
                                                      const int* __restrict__ dst,
                                                      int* __restrict__ G) {
    __shared__ int h[256];
    int bid = blockIdx.x;
    int t = threadIdx.x;
    if (bid >= PREP_BLKS) {
        // p1: per-block bucket histogram (bucket = dst >> 8)
        int blk = bid - PREP_BLKS;
        h[t] = 0;
        __syncthreads();
        int base = blk * CHUNK_SORT;
        for (int i = t; i < CHUNK_SORT; i += 256)
            atomicAdd(&h[dst[base + i] >> 8], 1);
        __syncthreads();
        G[blk * 256 + t] = h[t];
        return;
    }
    int idx = bid * 256 + t;
    if (idx < PREP_S0) {
        float4 v = x4[idx];
        ushort4 o;
        o.x = f2b(v.x); o.y = f2b(v.y); o.z = f2b(v.z); o.w = f2b(v.w);
        xb4[idx] = o;
    } else if (idx < PREP_S1) {
        int i = idx - PREP_S0;
        B1p[i] = packBK_elem(W1s, W1n, 64, 256, i);
    } else if (idx < PREP_S2) {
        int i = idx - PREP_S1;
        B2p[i] = packBN_elem(W2s, W2n, 128, 256, i);
    } else if (idx < PREP_S3) {
        int i = idx - PREP_S2;
        Bl1p[i] = packBK_elem(Wl1, Wl1, 128, 64, i);
    } else {
        int i = idx - PREP_S3;
        Bl2p[i] = packBK_elem(Wl2, Wl2, 64, 32, i);
    }
}

// ---------------- CSR build: parallel scans, no global atomics ----------------

// p2a: one block per bucket column b — scan G[0..NBLK-1][b] (pair-loaded, 2 per thread)
__global__ __launch_bounds__(256) void p2a_scan(int* __restrict__ G,
                                                int* __restrict__ colsum) {
    __shared__ int sc[256];
    int b = blockIdx.x;
    int t = threadIdx.x;
    int j0 = 2 * t, j1 = 2 * t + 1;
    int v0 = (j0 < NBLK_SORT) ? G[j0 * 256 + b] : 0;
    int v1 = (j1 < NBLK_SORT) ? G[j1 * 256 + b] : 0;
    int v = v0 + v1;
    sc[t] = v;
    __syncthreads();
    for (int off = 1; off < 256; off <<= 1) {
        int add = (t >= off) ? sc[t - off] : 0;
        __syncthreads();
        sc[t] += add;
        __syncthreads();
    }
    int ex = sc[t] - v;  // exclusive over pairs
    if (j0 < NBLK_SORT) G[j0 * 256 + b] = ex;
    if (j1 < NBLK_SORT) G[j1 * 256 + b] = ex + v0;
    if (t == 255) colsum[b] = sc[255];
}

// p3: scatter edges into bucket-grouped arrays via LDS cursors.
// Bucket offsets recomputed in-LDS from colsum.
__global__ __launch_bounds__(256) void p3_scatter(const int* __restrict__ src,
                                                  const int* __restrict__ dst,
                                                  const float* __restrict__ w,
                                                  const int* __restrict__ G,
                                                  const int* __restrict__ colsum,
                                                  int* __restrict__ bdst,
                                                  int2* __restrict__ bsedge) {
    __shared__ int cur[256];
    __shared__ int sc[256];
    int t = threadIdx.x;
    int v = colsum[t];
    sc[t] = v;
    __syncthreads();
    for (int off = 1; off < 256; off <<= 1) {
        int add = (t >= off) ? sc[t - off] : 0;
        __syncthreads();
        sc[t] += add;
        __syncthreads();
    }
    cur[t] = G[blockIdx.x * 256 + t] + (sc[t] - v);  // block prefix + bucket offset
    __syncthreads();
    int base = blockIdx.x * CHUNK_SORT;
    for (int i = t; i < CHUNK_SORT; i += 256) {
        int e = base + i;
        int d = dst[e];
        int pos = atomicAdd(&cur[d >> 8], 1);
        bdst[pos] = d;
        bsedge[pos] = make_int2(src[e], __float_as_int(w[e]));
    }
}

// p4: one block per bucket — LDS counting sort by dst, emit row_off/inv_deg/sedge
__global__ __launch_bounds__(256) void p4_sort(const int* __restrict__ colsum,
                                               const int* __restrict__ bdst,
                                               const int2* __restrict__ bsedge,
                                               int* __restrict__ row_off,
                                               float* __restrict__ inv_deg,
                                               int2* __restrict__ sedge) {
    __shared__ int lcnt[256];
    __shared__ int lcur[256];
    __shared__ int sc[256];
    __shared__ int sE0, sE1;
    int t = threadIdx.x;
    int b = blockIdx.x;
    // recompute bucket offsets from colsum (inclusive scan)
    int cv = colsum[t];
    sc[t] = cv;
    __syncthreads();
    for (int off = 1; off < 256; off <<= 1) {
        int add = (t >= off) ? sc[t - off] : 0;
        __syncthreads();
        sc[t] += add;
        __syncthreads();
    }
    if (t == b) { sE0 = sc[t] - cv; sE1 = sc[t]; }
    lcnt[t] = 0;
    __syncthreads();
    int e0 = sE0, e1 = sE1;
    int d0 = b << 8;
    for (int e = e0 + t; e < e1; e += 256)
        atomicAdd(&lcnt[bdst[e] - d0], 1);
    __syncthreads();
    int v = lcnt[t];
    sc[t] = v;
    __syncthreads();
    for (int off = 1; off < 256; off <<= 1) {
        int add = (t >= off) ? sc[t - off] : 0;
        __syncthreads();
        sc[t] += add;
        __syncthreads();
    }
    int loff = e0 + sc[t] - v;  // exclusive, global
    lcur[t] = loff;
    int d = d0 + t;
    if (d < N_NODES) {
        row_off[d] = loff;
        inv_deg[d] = 1.0f / (float)(v > 0 ? v : 1);
    }
    if (b == 0 && t == 0) row_off[N_NODES] = N_EDGES;
    __syncthreads();
    for (int e = e0 + t; e < e1; e += 256) {
        int dd = bdst[e];
        int2 sv = bsedge[e];
        int pos = atomicAdd(&lcur[dd - d0], 1);
        sedge[pos] = sv;
    }
}

// ---------------- Aggregations (gather; 4 waves/block, 1 node/wave) ----------------
// All edge slots in a 16-edge chunk are issued in parallel (clamped index +
// zeroed weight for out-of-range slots).

// d=64: eighth-wave per edge (8 lanes x dwordx4); 16 edges in flight per wave
__global__ __launch_bounds__(256) void agg64_kernel(const uint4* __restrict__ xb4,
                                                    const int* __restrict__ row_off,
                                                    const int2* __restrict__ sedge,
                                                    const float* __restrict__ inv_deg,
                                                    uint4* __restrict__ hn1b4) {
    int tid = threadIdx.x;
    int lane = tid & 63;
    int er = lane >> 3;   // edge slot 0..7
    int l7 = lane & 7;    // dim slot (8 bf16 each)
    int n = blockIdx.x * 4 + (tid >> 6);
    if (n >= N_NODES) return;
    int e0 = row_off[n], e1 = row_off[n + 1];
    float id = inv_deg[n];
    float a[8];
    #pragma unroll
    for (int j = 0; j < 8; j++) a[j] = 0.f;
    int e1m1 = e1 - 1;
    for (int e = e0; e < e1; e += 16) {
        int2 m[2];
        uint4 p[2];
        float w[2];
        #pragma unroll
        for (int k = 0; k < 2; k++) {
            int ee = e + k * 8 + er;
            int idx = ee < e1 ? ee : e1m1;
            m[k] = sedge[idx];
        }
        #pragma unroll
        for (int k = 0; k < 2; k++) {
            p[k] = xb4[m[k].x * 8 + l7];
            int ee = e + k * 8 + er;
            w[k] = (ee < e1) ? __int_as_float(m[k].y) : 0.f;
        }
        #pragma unroll
        for (int k = 0; k < 2; k++) {
            a[0] += w[k] * blo(p[k].x); a[1] += w[k] * bhi(p[k].x);
            a[2] += w[k] * blo(p[k].y); a[3] += w[k] * bhi(p[k].y);
            a[4] += w[k] * blo(p[k].z); a[5] += w[k] * bhi(p[k].z);
            a[6] += w[k] * blo(p[k].w); a[7] += w[k] * bhi(p[k].w);
        }
    }
    #pragma unroll
    for (int j = 0; j < 8; j++) {
        a[j] += __shfl_xor(a[j], 8, 64);
        a[j] += __shfl_xor(a[j], 16, 64);
        a[j] += __shfl_xor(a[j], 32, 64);
    }
    if (er == 0) {
        uint4 o;
        o.x = (unsigned)f2b(a[0] * id) | ((unsigned)f2b(a[1] * id) << 16);
        o.y = (unsigned)f2b(a[2] * id) | ((unsigned)f2b(a[3] * id) << 16);
        o.z = (unsigned)f2b(a[4] * id) | ((unsigned)f2b(a[5] * id) << 16);
        o.w = (unsigned)f2b(a[6] * id) | ((unsigned)f2b(a[7] * id) << 16);
        hn1b4[n * 8 + l7] = o;
    }
}

// d=128: quarter-wave per edge (16 lanes x dwordx4); 16 edges in flight per wave
__global__ __launch_bounds__(256) void agg128_kernel(const uint4* __restrict__ zb4,
                                                     const int* __restrict__ row_off,
                                                     const int2* __restrict__ sedge,
                                                     const float* __restrict__ inv_deg,
                                                     float* __restrict__ emb) {
    int tid = threadIdx.x;
    int lane = tid & 63;
    int qr = lane >> 4;   // edge slot 0..3
    int l15 = lane & 15;  // dim slot (8 bf16 each)
    int n = blockIdx.x * 4 + (tid >> 6);
    if (n >= N_NODES) return;
    int e0 = row_off[n], e1 = row_off[n + 1];
    float id = inv_deg[n];
    // prefetch self row early so it overlaps the gather phase
    float4 s0, s1;
    if (qr == 0) {
        s0 = ((const float4*)emb)[n * 32 + l15 * 2];
        s1 = ((const float4*)emb)[n * 32 + l15 * 2 + 1];
    }
    float a[8];
    #pragma unroll
    for (int j = 0; j < 8; j++) a[j] = 0.f;
    int e1m1 = e1 - 1;
    for (int e = e0; e < e1; e += 16) {
        int2 m[4];
        uint4 p[4];
        float w[4];
        #pragma unroll
        for (int k = 0; k < 4; k++) {
            int ee = e + k * 4 + qr;
            int idx = ee < e1 ? ee : e1m1;
            m[k] = sedge[idx];
        }
        #pragma unroll
        for (int k = 0; k < 4; k++) {
            p[k] = zb4[m[k].x * 16 + l15];
            int ee = e + k * 4 + qr;
            w[k] = (ee < e1) ? __int_as_float(m[k].y) : 0.f;
        }
        #pragma unroll
        for (int k = 0; k < 4; k++) {
            a[0] += w[k] * blo(p[k].x); a[1] += w[k] * bhi(p[k].x);
            a[2] += w[k] * blo(p[k].y); a[3] += w[k] * bhi(p[k].y);
            a[4] += w[k] * blo(p[k].z); a[5] += w[k] * bhi(p[k].z);
            a[6] += w[k] * blo(p[k].w); a[7] += w[k] * bhi(p[k].w);
        }
    }
    #pragma unroll
    for (int j = 0; j < 8; j++) {
        a[j] += __shfl_xor(a[j], 16, 64);
        a[j] += __shfl_xor(a[j], 32, 64);
    }
    if (qr == 0) {
        float v0 = s0.x + a[0] * id;
        float v1 = s0.y + a[1] * id;
        float v2 = s0.z + a[2] * id;
        float v3 = s0.w + a[3] * id;
        float v4 = s1.x + a[4] * id;
        float v5 = s1.y + a[5] * id;
        float v6 = s1.z + a[6] * id;
        float v7 = s1.w + a[7] * id;
        ((float4*)emb)[n * 32 + l15 * 2]     = make_float4(v0, v1, v2, v3);
        ((float4*)emb)[n * 32 + l15 * 2 + 1] = make_float4(v4, v5, v6, v7);
    }
}

// ---------------- Fused layer GEMMs: x1 lives only in LDS ----------------
// phase1: x1 = relu([xb|hn1b] @ [W1s;W1n] + b1)  K=128, N=256  -> xS (bf16)
// phase2: [emb_self|z] = x1 @ [W2s|W2n]          K=256, N=256
// B staged per-kt through a single 16 KB LDS buffer with register prefetch.
__global__ __launch_bounds__(256) void gemm12_mfma(const unsigned short* __restrict__ xb,
                                                   const unsigned short* __restrict__ hn1b,
                                                   const unsigned short* __restrict__ B1p,
                                                   const float* __restrict__ b1,
                                                   const unsigned short* __restrict__ B2p,
                                                   const float* __restrict__ b2,
                                                   float* __restrict__ emb,
                                                   unsigned short* __restrict__ zb) {
    __shared__ __align__(16) unsigned short xS[64 * 264];  // 33792 B, wave-private 16-row slabs
    __shared__ __align__(16) unsigned short sB[8192];      // 16384 B
    int tid = threadIdx.x;
    int lane = tid & 63;
    int wv = tid >> 6;
    int mt = blockIdx.x * 4 + wv;
    if (mt >= MT_TILES) mt = MT_TILES - 1;  // dup wave, benign same-value stores
    int q = lane >> 4;
    int rl = lane & 15;
    int row = mt * 16 + rl;
    frag_ab a[4];
    a[0] = *(const frag_ab*)(xb + row * 64 + q * 8);
    a[1] = *(const frag_ab*)(xb + row * 64 + q * 8 + 32);
    a[2] = *(const frag_ab*)(hn1b + row * 64 + q * 8);
    a[3] = *(const frag_ab*)(hn1b + row * 64 + q * 8 + 32);
    frag_cd acc[16];
    #pragma unroll
    for (int nt = 0; nt < 16; nt++) acc[nt] = (frag_cd){0.f, 0.f, 0.f, 0.f};
    const float4* gB = (const float4*)B1p;   // 1024 float4 per kt
    float4 s0 = gB[tid], s1 = gB[256 + tid], s2 = gB[512 + tid], s3 = gB[768 + tid];
    #pragma unroll
    for (int kt = 0; kt < 4; kt++) {
        __syncthreads();
        ((float4*)sB)[tid] = s0;
        ((float4*)sB)[256 + tid] = s1;
        ((float4*)sB)[512 + tid] = s2;
        ((float4*)sB)[768 + tid] = s3;
        __syncthreads();
        if (kt < 3) {
            s0 = gB[(kt + 1) * 1024 + tid];       s1 = gB[(kt + 1) * 1024 + 256 + tid];
            s2 = gB[(kt + 1) * 1024 + 512 + tid]; s3 = gB[(kt + 1) * 1024 + 768 + tid];
        }
        #pragma unroll
        for (int nt = 0; nt < 16; nt++) {
            frag_ab b = *(const frag_ab*)(sB + (nt * 64 + lane) * 8);
            acc[nt] = __builtin_amdgcn_mfma_f32_16x16x32_bf16(a[kt], b, acc[nt], 0, 0, 0);
        }
    }
    // epilogue 1: bias+relu -> xS bf16 (wave-private rows, padded stride 264)
    #pragma unroll
    for (int nt = 0; nt < 16; nt++) {
        int c = nt * 16 + rl;
        float bias = b1[c];
        #pragma unroll
        for (int i = 0; i < 4; i++) {
            float v = acc[nt][i] + bias;
            v = v > 0.f ? v : 0.f;
            xS[(wv * 16 + q * 4 + i) * 264 + c] = f2b(v);
        }
    }
    // phase 2: K=256 (8 kt), A from xS
    const float4* gB2 = (const float4*)B2p;
    s0 = gB2[tid]; s1 = gB2[256 + tid]; s2 = gB2[512 + tid]; s3 = gB2[768 + tid];
    frag_cd acc2[16];
    #pragma unroll
    for (int nt = 0; nt < 16; nt++) acc2[nt] = (frag_cd){0.f, 0.f, 0.f, 0.f};
    const unsigned short* a2base = xS + (wv * 16 + rl) * 264 + q * 8;
    #pragma unroll
    for (int kt = 0; kt < 8; kt++) {
        __syncthreads();   // kt=0: covers xS writes + phase1's last sB reads
        ((float4*)sB)[tid] = s0;
        ((float4*)sB)[256 + tid] = s1;
        ((float4*)sB)[512 + tid] = s2;
        ((float4*)sB)[768 + tid] = s3;
        __syncthreads();
        if (kt < 7) {
            s0 = gB2[(kt + 1) * 1024 + tid];       s1 = gB2[(kt + 1) * 1024 + 256 + tid];
            s2 = gB2[(kt + 1) * 1024 + 512 + tid]; s3 = gB2[(kt + 1) * 1024 + 768 + tid];
        }
        frag_ab a2 = *(const frag_ab*)(a2base + kt * 32);
        #pragma unroll
        for (int nt = 0; nt < 16; nt++) {
            frag_ab b = *(const frag_ab*)(sB + (nt * 64 + lane) * 8);
            acc2[nt] = __builtin_amdgcn_mfma_f32_16x16x32_bf16(a2, b, acc2[nt], 0, 0, 0);
        }
    }
    int r0 = mt * 16;
    #pragma unroll
    for (int nt = 0; nt < 8; nt++) {
        int c = nt * 16 + rl;
        float bias = b2[c];
        #pragma unroll
        for (int i = 0; i < 4; i++) {
            int r = r0 + q * 4 + i;
            emb[r * 128 + c] = acc2[nt][i] + bias;
        }
    }
    #pragma unroll
    for (int nt = 8; nt < 16; nt++) {
        int c = (nt - 8) * 16 + rl;
        #pragma unroll
        for (int i = 0; i < 4; i++) {
            int r = r0 + q * 4 + i;
            zb[r * 128 + c] = f2b(acc2[nt][i]);
        }
    }
}

// fused MLP head: h64 = relu(bf16(emb) @ Wl1 + bl1) (LDS bf16, padded stride 72),
// h32 = relu(h64 @ Wl2 + bl2) (LDS fp32), out = h32 @ Wl3 + bl3
__global__ __launch_bounds__(256) void mlp_fused(const float* __restrict__ emb,
                                                 const unsigned short* __restrict__ B1,
                                                 const float* __restrict__ bl1,
                                                 const unsigned short* __restrict__ B2,
                                                 const float* __restrict__ bl2,
                                                 const float* __restrict__ Wl3,
                                                 const float* __restrict__ bl3,
                                                 float* __restrict__ out) {
    __shared__ __align__(16) unsigned short h64s[64 * 72];  // stride 72 breaks bank aliasing
    __shared__ float hs[64][33];
    int tid = threadIdx.x;
    int lane = tid & 63;
    int wv = tid >> 6;
    int mt = blockIdx.x * 4 + wv;
    if (mt >= MT_TILES) mt = MT_TILES - 1;
    int q = lane >> 4;
    int rl = lane & 15;
    // stage 1: K=128 (4 kt), N=64 (4 nt); A built from fp32 emb on the fly
    const frag_ab* bp1 = (const frag_ab*)B1;
    frag_cd acc[4];
    #pragma unroll
    for (int nt = 0; nt < 4; nt++) acc[nt] = (frag_cd){0.f, 0.f, 0.f, 0.f};
    #pragma unroll
    for (int kt = 0; kt < 4; kt++) {
        const float4* ap = (const float4*)(emb + (mt * 16 + rl) * 128 + kt * 32 + q * 8);
        float4 f0 = ap[0], f1 = ap[1];
        frag_ab a;
        a[0] = (short)f2b(f0.x); a[1] = (short)f2b(f0.y);
        a[2] = (short)f2b(f0.z); a[3] = (short)f2b(f0.w);
        a[4] = (short)f2b(f1.x); a[5] = (short)f2b(f1.y);
        a[6] = (short)f2b(f1.z); a[7] = (short)f2b(f1.w);
        #pragma unroll
        for (int nt = 0; nt < 4; nt++)
            acc[nt] = __builtin_amdgcn_mfma_f32_16x16x32_bf16(a, bp1[(kt * 4 + nt) * 64 + lane], acc[nt], 0, 0, 0);
    }
    #pragma unroll
    for (int nt = 0; nt < 4; nt++) {
        int c = nt * 16 + rl;
        float bias = bl1[c];
        #pragma unroll
        for (int i = 0; i < 4; i++) {
            float v = acc[nt][i] + bias;
            h64s[(wv * 16 + q * 4 + i) * 72 + c] = f2b(v > 0.f ? v : 0.f);
        }
    }
    __syncthreads();
    // stage 2: K=64 (2 kt), N=32 (2 nt); A from LDS
    const unsigned short* a2 = h64s + (wv * 16 + rl) * 72 + q * 8;
    const frag_ab* bp2 = (const frag_ab*)B2;
    frag_cd acc2[2];
    #pragma unroll
    for (int nt = 0; nt < 2; nt++) acc2[nt] = (frag_cd){0.f, 0.f, 0.f, 0.f};
    #pragma unroll
    for (int kt = 0; kt < 2; kt++) {
        frag_ab a = *(const frag_ab*)(a2 + kt * 32);
        #pragma unroll
        for (int nt = 0; nt < 2; nt++)
            acc2[nt] = __builtin_amdgcn_mfma_f32_16x16x32_bf16(a, bp2[(kt * 2 + nt) * 64 + lane], acc2[nt], 0, 0, 0);
    }
    #pragma unroll
    for (int nt = 0; nt < 2; nt++) {
        int c = nt * 16 + rl;
        float bias = bl2[c];
        #pragma unroll
        for (int i = 0; i < 4; i++) {
            int lr = wv * 16 + q * 4 + i;
            float v = acc2[nt][i] + bias;
            hs[lr][c] = v > 0.f ? v : 0.f;
        }
    }
    __syncthreads();
    int base = blockIdx.x * 64;
    for (int idx = tid; idx < 640; idx += 256) {
        int lr = idx / 10;
        int j = idx - lr * 10;
        int n = base + lr;
        if (n < N_NODES) {
            float a = bl3[j];
            #pragma unroll
            for (int k = 0; k < 32; k++) a += hs[lr][k] * Wl3[k * 10 + j];
            out[n * 10 + j] = a;
        }
    }
}

// ---------------- launch ----------------

extern "C" void kernel_launch(void* const* d_in, const int* in_sizes, int n_in,
                              void* d_out, int out_size, void* d_ws, size_t ws_size,
                              hipStream_t stream) {
    const float* x   = (const float*)d_in[0];
    const int* esrc  = (const int*)d_in[1];
    const int* edst  = (const int*)d_in[2];
    const float* ew  = (const float*)d_in[3];
    const float* W1s = (const float*)d_in[4];
    const float* W1n = (const float*)d_in[5];
    const float* b1  = (const float*)d_in[6];
    const float* W2s = (const float*)d_in[7];
    const float* W2n = (const float*)d_in[8];
    const float* b2  = (const float*)d_in[9];
    const float* Wl1 = (const float*)d_in[10];
    const float* bl1 = (const float*)d_in[11];
    const float* Wl2 = (const float*)d_in[12];
    const float* bl2 = (const float*)d_in[13];
    const float* Wl3 = (const float*)d_in[14];
    const float* bl3 = (const float*)d_in[15];

    float* out = (float*)d_out;       // [50000,10]
    float* emb = out + 500000;        // [50000,128] output 1

    char* ws = (char*)d_ws;
    size_t off = 0;
    auto alloc = [&](size_t bytes) -> void* {
        void* p = ws + off;
        off = (off + bytes + 255) & ~(size_t)255;
        return p;
    };
    int*   row_off = (int*)alloc((size_t)(N_NODES + 1) * 4);
    float* inv_deg = (float*)alloc((size_t)N_NODES * 4);
    int*   G       = (int*)alloc((size_t)NBLK_SORT * 256 * 4);
    int*   colsum  = (int*)alloc(256 * 4);
    int*   bdst    = (int*)alloc((size_t)N_EDGES * 4);
    int2*  bsedge  = (int2*)alloc((size_t)N_EDGES * 8);
    int2*  sedge   = (int2*)alloc((size_t)N_EDGES * 8);
    unsigned short* xb   = (unsigned short*)alloc((size_t)N_NODES * 64 * 2);
    unsigned short* hn1b = (unsigned short*)alloc((size_t)N_NODES * 64 * 2);
    unsigned short* zb   = (unsigned short*)alloc((size_t)N_NODES * 128 * 2);
    unsigned short* B1p  = (unsigned short*)alloc(128 * 256 * 2);
    unsigned short* B2p  = (unsigned short*)alloc(256 * 256 * 2);
    unsigned short* Bl1p = (unsigned short*)alloc(128 * 64 * 2);
    unsigned short* Bl2p = (unsigned short*)alloc(64 * 32 * 2);

    // fused cvt + weight packing + p1 histogram
    prep_p1_kernel<<<PREP_BLKS + NBLK_SORT, 256, 0, stream>>>(
        (const float4*)x, (ushort4*)xb, W1s, W1n, W2s, W2n, Wl1, Wl2,
        B1p, B2p, Bl1p, Bl2p, edst, G);

    // parallel scans + scatter + per-bucket sort
    p2a_scan<<<256, 256, 0, stream>>>(G, colsum);
    p3_scatter<<<NBLK_SORT, 256, 0, stream>>>(esrc, edst, ew, G, colsum, bdst, bsedge);
    p4_sort<<<NBKT, 256, 0, stream>>>(colsum, bdst, bsedge, row_off, inv_deg, sedge);

    const int GBLK = (MT_TILES + 3) / 4;   // 782
    const int ABLK = (N_NODES + 3) / 4;    // 12500

    // layer 1 aggregate, then fused layer-1+2 GEMM (x1 never leaves LDS)
    agg64_kernel<<<ABLK, 256, 0, stream>>>((const uint4*)xb, row_off, sedge,
                                           inv_deg, (uint4*)hn1b);
    gemm12_mfma<<<GBLK, 256, 0, stream>>>(xb, hn1b, B1p, b1, B2p, b2, emb, zb);

    // layer-2 aggregate (adds neighbor term into emb)
    agg128_kernel<<<ABLK, 256, 0, stream>>>((const uint4*)zb, row_off, sedge,
                                            inv_deg, emb);

    // fused MLP head (reads fp32 emb, converts on the fly)
    mlp_fused<<<GBLK, 256, 0, stream>>>(emb, Bl1p, bl1, Bl2p, bl2, Wl3, bl3, out);
}

// Round 4
// 235.018 us; speedup vs baseline: 1.0284x; 1.0284x over previous
//
#include <hip/hip_runtime.h>
#include <hip/hip_bf16.h>

#define N_NODES 50000
#define N_EDGES 800000
#define MT_TILES 3125   // 50000 / 16

#define NBLK_SORT 400
#define CHUNK_SORT 2000   // NBLK_SORT * CHUNK_SORT == N_EDGES
#define NBKT 196          // ceil(50000 / 256)

typedef __attribute__((ext_vector_type(8))) short frag_ab;   // 8 bf16 (4 VGPRs)
typedef __attribute__((ext_vector_type(4))) float frag_cd;   // 4 fp32 acc

static __device__ __forceinline__ unsigned short f2b(float f) {
    union { float f; unsigned u; } v; v.f = f;
    unsigned r = v.u + 0x7fffu + ((v.u >> 16) & 1u);  // RNE
    return (unsigned short)(r >> 16);
}
static __device__ __forceinline__ float b2f(unsigned short b) {
    union { float f; unsigned u; } v; v.u = ((unsigned)b) << 16;
    return v.f;
}
static __device__ __forceinline__ float blo(unsigned p) { return b2f((unsigned short)(p & 0xffffu)); }
static __device__ __forceinline__ float bhi(unsigned p) { return b2f((unsigned short)(p >> 16)); }

// ---------------- fused prep (cvt x, pack weights) + p1 bucket histogram ----------------
static __device__ __forceinline__ unsigned short packBK_elem(const float* __restrict__ Wa,
                                                             const float* __restrict__ Wb,
                                                             int Ka, int N, int idx) {
    int j = idx & 7;
    int lane = (idx >> 3) & 63;
    int rest = idx >> 9;
    int ntiles = N >> 4;
    int nt = rest % ntiles;
    int kt = rest / ntiles;
    int kk = kt * 32 + (lane >> 4) * 8 + j;
    int nn = nt * 16 + (lane & 15);
    float v = (kk < Ka) ? Wa[kk * N + nn] : Wb[(kk - Ka) * N + nn];
    return f2b(v);
}
static __device__ __forceinline__ unsigned short packBN_elem(const float* __restrict__ Wa,
                                                             const float* __restrict__ Wb,
                                                             int Na, int N, int idx) {
    int j = idx & 7;
    int lane = (idx >> 3) & 63;
    int rest = idx >> 9;
    int ntiles = N >> 4;
    int nt = rest % ntiles;
    int kt = rest / ntiles;
    int kk = kt * 32 + (lane >> 4) * 8 + j;
    int nn = nt * 16 + (lane & 15);
    float v = (nn < Na) ? Wa[kk * Na + nn] : Wb[kk * (N - Na) + (nn - Na)];
    return f2b(v);
}

#define PREP_S0 800000                 // cvt: ushort4 items (N_NODES*64/4)
#define PREP_S1 (PREP_S0 + 32768)      // B1p  128x256
#define PREP_S2 (PREP_S1 + 65536)      // B2p  256x256
#define PREP_S3 (PREP_S2 + 8192)      // Bl1p 128x64
#define PREP_S4 (PREP_S3 + 2048)      // Bl2p 64x32   -> total 908544 = 3549*256
#define PREP_BLKS 3549

__global__ __launch_bounds__(256) void prep_p1_kernel(const float4* __restrict__ x4,
                                                      ushort4* __restrict__ xb4,
                                                      const float* __restrict__ W1s,
                                                      const float* __restrict__ W1n,
                                                      const float* __restrict__ W2s,
                                                      const float* __restrict__ W2n,
                                                      const float* __restrict__ Wl1,
                                                      const float* __restrict__ Wl2,
                                                      unsigned short* __restrict__ B1p,
                                                      unsigned short* __restrict__ B2p,
                                                      unsigned short* __restrict__ Bl1p,
                                                      unsigned short* __restrict__ Bl2p,
                                                      const int* __restrict__ dst,
                                                      int* __restrict__ G) {
    __shared__ int h[256];
    int bid = blockIdx.x;
    int t = threadIdx.x;
    if (bid >= PREP_BLKS) {
        // p1: per-block bucket histogram (bucket = dst >> 8)
        int blk = bid - PREP_BLKS;
        h[t] = 0;
        __syncthreads();
        int base = blk * CHUNK_SORT;
        for (int i = t; i < CHUNK_SORT; i += 256)
            atomicAdd(&h[dst[base + i] >> 8], 1);
        __syncthreads();
        G[blk * 256 + t] = h[t];
        return;
    }
    int idx = bid * 256 + t;
    if (idx < PREP_S0) {
        float4 v = x4[idx];
        ushort4 o;
        o.x = f2b(v.x); o.y = f2b(v.y); o.z = f2b(v.z); o.w = f2b(v.w);
        xb4[idx] = o;
    } else if (idx < PREP_S1) {
        int i = idx - PREP_S0;
        B1p[i] = packBK_elem(W1s, W1n, 64, 256, i);
    } else if (idx < PREP_S2) {
        int i = idx - PREP_S1;
        B2p[i] = packBN_elem(W2s, W2n, 128, 256, i);
    } else if (idx < PREP_S3) {
        int i = idx - PREP_S2;
        Bl1p[i] = packBK_elem(Wl1, Wl1, 128, 64, i);
    } else {
        int i = idx - PREP_S3;
        Bl2p[i] = packBK_elem(Wl2, Wl2, 64, 32, i);
    }
}

// ---------------- CSR build: parallel scans, no global atomics ----------------

// p2a: one block per bucket column b — scan G[0..NBLK-1][b] (pair-loaded, 2 per thread)
__global__ __launch_bounds__(256) void p2a_scan(int* __restrict__ G,
                                                int* __restrict__ colsum) {
    __shared__ int sc[256];
    int b = blockIdx.x;
    int t = threadIdx.x;
    int j0 = 2 * t, j1 = 2 * t + 1;
    int v0 = (j0 < NBLK_SORT) ? G[j0 * 256 + b] : 0;
    int v1 = (j1 < NBLK_SORT) ? G[j1 * 256 + b] : 0;
    int v = v0 + v1;
    sc[t] = v;
    __syncthreads();
    for (int off = 1; off < 256; off <<= 1) {
        int add = (t >= off) ? sc[t - off] : 0;
        __syncthreads();
        sc[t] += add;
        __syncthreads();
    }
    int ex = sc[t] - v;  // exclusive over pairs
    if (j0 < NBLK_SORT) G[j0 * 256 + b] = ex;
    if (j1 < NBLK_SORT) G[j1 * 256 + b] = ex + v0;
    if (t == 255) colsum[b] = sc[255];
}

// p3: scatter edges into bucket-grouped arrays via LDS cursors.
// Bucket offsets recomputed in-LDS from colsum.
__global__ __launch_bounds__(256) void p3_scatter(const int* __restrict__ src,
                                                  const int* __restrict__ dst,
                                                  const float* __restrict__ w,
                                                  const int* __restrict__ G,
                                                  const int* __restrict__ colsum,
                                                  int* __restrict__ bdst,
                                                  int2* __restrict__ bsedge) {
    __shared__ int cur[256];
    __shared__ int sc[256];
    int t = threadIdx.x;
    int v = colsum[t];
    sc[t] = v;
    __syncthreads();
    for (int off = 1; off < 256; off <<= 1) {
        int add = (t >= off) ? sc[t - off] : 0;
        __syncthreads();
        sc[t] += add;
        __syncthreads();
    }
    cur[t] = G[blockIdx.x * 256 + t] + (sc[t] - v);  // block prefix + bucket offset
    __syncthreads();
    int base = blockIdx.x * CHUNK_SORT;
    for (int i = t; i < CHUNK_SORT; i += 256) {
        int e = base + i;
        int d = dst[e];
        int pos = atomicAdd(&cur[d >> 8], 1);
        bdst[pos] = d;
        bsedge[pos] = make_int2(src[e], __float_as_int(w[e]));
    }
}

// p4: one block per bucket — LDS counting sort by dst, emit row_off/inv_deg/sedge
__global__ __launch_bounds__(256) void p4_sort(const int* __restrict__ colsum,
                                               const int* __restrict__ bdst,
                                               const int2* __restrict__ bsedge,
                                               int* __restrict__ row_off,
                                               float* __restrict__ inv_deg,
                                               int2* __restrict__ sedge) {
    __shared__ int lcnt[256];
    __shared__ int lcur[256];
    __shared__ int sc[256];
    __shared__ int sE0, sE1;
    int t = threadIdx.x;
    int b = blockIdx.x;
    // recompute bucket offsets from colsum (inclusive scan)
    int cv = colsum[t];
    sc[t] = cv;
    __syncthreads();
    for (int off = 1; off < 256; off <<= 1) {
        int add = (t >= off) ? sc[t - off] : 0;
        __syncthreads();
        sc[t] += add;
        __syncthreads();
    }
    if (t == b) { sE0 = sc[t] - cv; sE1 = sc[t]; }
    lcnt[t] = 0;
    __syncthreads();
    int e0 = sE0, e1 = sE1;
    int d0 = b << 8;
    for (int e = e0 + t; e < e1; e += 256)
        atomicAdd(&lcnt[bdst[e] - d0], 1);
    __syncthreads();
    int v = lcnt[t];
    sc[t] = v;
    __syncthreads();
    for (int off = 1; off < 256; off <<= 1) {
        int add = (t >= off) ? sc[t - off] : 0;
        __syncthreads();
        sc[t] += add;
        __syncthreads();
    }
    int loff = e0 + sc[t] - v;  // exclusive, global
    lcur[t] = loff;
    int d = d0 + t;
    if (d < N_NODES) {
        row_off[d] = loff;
        inv_deg[d] = 1.0f / (float)(v > 0 ? v : 1);
    }
    if (b == 0 && t == 0) row_off[N_NODES] = N_EDGES;
    __syncthreads();
    for (int e = e0 + t; e < e1; e += 256) {
        int dd = bdst[e];
        int2 sv = bsedge[e];
        int pos = atomicAdd(&lcur[dd - d0], 1);
        sedge[pos] = sv;
    }
}

// ---------------- Aggregations (gather; 4 waves/block, 1 node/wave) ----------------
// All edge slots in a 16-edge chunk are issued in parallel (clamped index +
// zeroed weight for out-of-range slots).

// d=64: eighth-wave per edge (8 lanes x dwordx4); 16 edges in flight per wave
__global__ __launch_bounds__(256) void agg64_kernel(const uint4* __restrict__ xb4,
                                                    const int* __restrict__ row_off,
                                                    const int2* __restrict__ sedge,
                                                    const float* __restrict__ inv_deg,
                                                    uint4* __restrict__ hn1b4) {
    int tid = threadIdx.x;
    int lane = tid & 63;
    int er = lane >> 3;   // edge slot 0..7
    int l7 = lane & 7;    // dim slot (8 bf16 each)
    int n = blockIdx.x * 4 + (tid >> 6);
    if (n >= N_NODES) return;
    int e0 = row_off[n], e1 = row_off[n + 1];
    float id = inv_deg[n];
    float a[8];
    #pragma unroll
    for (int j = 0; j < 8; j++) a[j] = 0.f;
    int e1m1 = e1 - 1;
    for (int e = e0; e < e1; e += 16) {
        int2 m[2];
        uint4 p[2];
        float w[2];
        #pragma unroll
        for (int k = 0; k < 2; k++) {
            int ee = e + k * 8 + er;
            int idx = ee < e1 ? ee : e1m1;
            m[k] = sedge[idx];
        }
        #pragma unroll
        for (int k = 0; k < 2; k++) {
            p[k] = xb4[m[k].x * 8 + l7];
            int ee = e + k * 8 + er;
            w[k] = (ee < e1) ? __int_as_float(m[k].y) : 0.f;
        }
        #pragma unroll
        for (int k = 0; k < 2; k++) {
            a[0] += w[k] * blo(p[k].x); a[1] += w[k] * bhi(p[k].x);
            a[2] += w[k] * blo(p[k].y); a[3] += w[k] * bhi(p[k].y);
            a[4] += w[k] * blo(p[k].z); a[5] += w[k] * bhi(p[k].z);
            a[6] += w[k] * blo(p[k].w); a[7] += w[k] * bhi(p[k].w);
        }
    }
    #pragma unroll
    for (int j = 0; j < 8; j++) {
        a[j] += __shfl_xor(a[j], 8, 64);
        a[j] += __shfl_xor(a[j], 16, 64);
        a[j] += __shfl_xor(a[j], 32, 64);
    }
    if (er == 0) {
        uint4 o;
        o.x = (unsigned)f2b(a[0] * id) | ((unsigned)f2b(a[1] * id) << 16);
        o.y = (unsigned)f2b(a[2] * id) | ((unsigned)f2b(a[3] * id) << 16);
        o.z = (unsigned)f2b(a[4] * id) | ((unsigned)f2b(a[5] * id) << 16);
        o.w = (unsigned)f2b(a[6] * id) | ((unsigned)f2b(a[7] * id) << 16);
        hn1b4[n * 8 + l7] = o;
    }
}

// d=128: quarter-wave per edge (16 lanes x dwordx4); 16 edges in flight per wave
__global__ __launch_bounds__(256) void agg128_kernel(const uint4* __restrict__ zb4,
                                                     const int* __restrict__ row_off,
                                                     const int2* __restrict__ sedge,
                                                     const float* __restrict__ inv_deg,
                                                     float* __restrict__ emb) {
    int tid = threadIdx.x;
    int lane = tid & 63;
    int qr = lane >> 4;   // edge slot 0..3
    int l15 = lane & 15;  // dim slot (8 bf16 each)
    int n = blockIdx.x * 4 + (tid >> 6);
    if (n >= N_NODES) return;
    int e0 = row_off[n], e1 = row_off[n + 1];
    float id = inv_deg[n];
    // prefetch self row early so it overlaps the gather phase
    float4 s0, s1;
    if (qr == 0) {
        s0 = ((const float4*)emb)[n * 32 + l15 * 2];
        s1 = ((const float4*)emb)[n * 32 + l15 * 2 + 1];
    }
    float a[8];
    #pragma unroll
    for (int j = 0; j < 8; j++) a[j] = 0.f;
    int e1m1 = e1 - 1;
    for (int e = e0; e < e1; e += 16) {
        int2 m[4];
        uint4 p[4];
        float w[4];
        #pragma unroll
        for (int k = 0; k < 4; k++) {
            int ee = e + k * 4 + qr;
            int idx = ee < e1 ? ee : e1m1;
            m[k] = sedge[idx];
        }
        #pragma unroll
        for (int k = 0; k < 4; k++) {
            p[k] = zb4[m[k].x * 16 + l15];
            int ee = e + k * 4 + qr;
            w[k] = (ee < e1) ? __int_as_float(m[k].y) : 0.f;
        }
        #pragma unroll
        for (int k = 0; k < 4; k++) {
            a[0] += w[k] * blo(p[k].x); a[1] += w[k] * bhi(p[k].x);
            a[2] += w[k] * blo(p[k].y); a[3] += w[k] * bhi(p[k].y);
            a[4] += w[k] * blo(p[k].z); a[5] += w[k] * bhi(p[k].z);
            a[6] += w[k] * blo(p[k].w); a[7] += w[k] * bhi(p[k].w);
        }
    }
    #pragma unroll
    for (int j = 0; j < 8; j++) {
        a[j] += __shfl_xor(a[j], 16, 64);
        a[j] += __shfl_xor(a[j], 32, 64);
    }
    if (qr == 0) {
        float v0 = s0.x + a[0] * id;
        float v1 = s0.y + a[1] * id;
        float v2 = s0.z + a[2] * id;
        float v3 = s0.w + a[3] * id;
        float v4 = s1.x + a[4] * id;
        float v5 = s1.y + a[5] * id;
        float v6 = s1.z + a[6] * id;
        float v7 = s1.w + a[7] * id;
        ((float4*)emb)[n * 32 + l15 * 2]     = make_float4(v0, v1, v2, v3);
        ((float4*)emb)[n * 32 + l15 * 2 + 1] = make_float4(v4, v5, v6, v7);
    }
}

// ---------------- MFMA GEMMs: 8 m-tiles/block (512 thr), double-buffered B staging ----------------

// x1b = bf16(relu([xb|hn1b] @ [W1s;W1n] + b1))   K=128 (4 kt), N=256
__global__ __launch_bounds__(512) void gemm1_mfma(const unsigned short* __restrict__ xb,
                                                  const unsigned short* __restrict__ hn1b,
                                                  const unsigned short* __restrict__ Bp,
                                                  const float* __restrict__ b1,
                                                  unsigned short* __restrict__ x1b) {
    __shared__ __align__(16) unsigned short sB[2][8192];
    int tid = threadIdx.x;
    int lane = tid & 63;
    int wv = tid >> 6;                 // 0..7
    int mt = blockIdx.x * 8 + wv;
    if (mt >= MT_TILES) mt = MT_TILES - 1;  // dup wave, benign same-value stores
    int q = lane >> 4;
    int rl = lane & 15;
    int row = mt * 16 + rl;
    frag_ab a[4];
    a[0] = *(const frag_ab*)(xb + row * 64 + q * 8);
    a[1] = *(const frag_ab*)(xb + row * 64 + q * 8 + 32);
    a[2] = *(const frag_ab*)(hn1b + row * 64 + q * 8);
    a[3] = *(const frag_ab*)(hn1b + row * 64 + q * 8 + 32);
    frag_cd acc[16];
    #pragma unroll
    for (int nt = 0; nt < 16; nt++) acc[nt] = (frag_cd){0.f, 0.f, 0.f, 0.f};
    const float4* gB = (const float4*)Bp;   // 1024 float4 per kt
    float4 s0 = gB[tid], s1 = gB[512 + tid];
    ((float4*)sB[0])[tid] = s0;
    ((float4*)sB[0])[512 + tid] = s1;
    #pragma unroll
    for (int kt = 0; kt < 4; kt++) {
        __syncthreads();
        if (kt < 3) { s0 = gB[(kt + 1) * 1024 + tid]; s1 = gB[(kt + 1) * 1024 + 512 + tid]; }
        const unsigned short* sb = sB[kt & 1];
        #pragma unroll
        for (int nt = 0; nt < 16; nt++) {
            frag_ab b = *(const frag_ab*)(sb + (nt * 64 + lane) * 8);
            acc[nt] = __builtin_amdgcn_mfma_f32_16x16x32_bf16(a[kt], b, acc[nt], 0, 0, 0);
        }
        if (kt < 3) {
            ((float4*)sB[(kt + 1) & 1])[tid] = s0;
            ((float4*)sB[(kt + 1) & 1])[512 + tid] = s1;
        }
    }
    int r0 = mt * 16;
    #pragma unroll
    for (int nt = 0; nt < 16; nt++) {
        int c = nt * 16 + rl;
        float bias = b1[c];
        #pragma unroll
        for (int i = 0; i < 4; i++) {
            int r = r0 + q * 4 + i;
            float v = acc[nt][i] + bias;
            v = v > 0.f ? v : 0.f;
            x1b[r * 256 + c] = f2b(v);
        }
    }
}

// self+z: x1b @ [W2s|W2n]; cols 0-127 -> emb fp32 (+b2), cols 128-255 -> zb bf16. K=256 (8 kt)
__global__ __launch_bounds__(512) void gemm2_mfma(const unsigned short* __restrict__ x1b,
                                                  const unsigned short* __restrict__ Bp,
                                                  const float* __restrict__ b2,
                                                  float* __restrict__ emb,
                                                  unsigned short* __restrict__ zb) {
    __shared__ __align__(16) unsigned short sB[2][8192];
    int tid = threadIdx.x;
    int lane = tid & 63;
    int wv = tid >> 6;
    int mt = blockIdx.x * 8 + wv;
    if (mt >= MT_TILES) mt = MT_TILES - 1;
    int q = lane >> 4;
    int rl = lane & 15;
    int row = mt * 16 + rl;
    const unsigned short* arow = x1b + row * 256 + q * 8;
    frag_ab a[8];
    #pragma unroll
    for (int kt = 0; kt < 8; kt++) a[kt] = *(const frag_ab*)(arow + kt * 32);
    frag_cd acc[16];
    #pragma unroll
    for (int nt = 0; nt < 16; nt++) acc[nt] = (frag_cd){0.f, 0.f, 0.f, 0.f};
    const float4* gB = (const float4*)Bp;
    float4 s0 = gB[tid], s1 = gB[512 + tid];
    ((float4*)sB[0])[tid] = s0;
    ((float4*)sB[0])[512 + tid] = s1;
    #pragma unroll
    for (int kt = 0; kt < 8; kt++) {
        __syncthreads();
        if (kt < 7) { s0 = gB[(kt + 1) * 1024 + tid]; s1 = gB[(kt + 1) * 1024 + 512 + tid]; }
        const unsigned short* sb = sB[kt & 1];
        #pragma unroll
        for (int nt = 0; nt < 16; nt++) {
            frag_ab b = *(const frag_ab*)(sb + (nt * 64 + lane) * 8);
            acc[nt] = __builtin_amdgcn_mfma_f32_16x16x32_bf16(a[kt], b, acc[nt], 0, 0, 0);
        }
        if (kt < 7) {
            ((float4*)sB[(kt + 1) & 1])[tid] = s0;
            ((float4*)sB[(kt + 1) & 1])[512 + tid] = s1;
        }
    }
    int r0 = mt * 16;
    #pragma unroll
    for (int nt = 0; nt < 8; nt++) {
        int c = nt * 16 + rl;
        float bias = b2[c];
        #pragma unroll
        for (int i = 0; i < 4; i++) {
            int r = r0 + q * 4 + i;
            emb[r * 128 + c] = acc[nt][i] + bias;
        }
    }
    #pragma unroll
    for (int nt = 8; nt < 16; nt++) {
        int c = (nt - 8) * 16 + rl;
        #pragma unroll
        for (int i = 0; i < 4; i++) {
            int r = r0 + q * 4 + i;
            zb[r * 128 + c] = f2b(acc[nt][i]);
        }
    }
}

// fused MLP head: h64 = relu(bf16(emb) @ Wl1 + bl1) (LDS bf16, padded stride 72),
// h32 = relu(h64 @ Wl2 + bl2) (LDS fp32), out = h32 @ Wl3 + bl3
__global__ __launch_bounds__(256) void mlp_fused(const float* __restrict__ emb,
                                                 const unsigned short* __restrict__ B1,
                                                 const float* __restrict__ bl1,
                                                 const unsigned short* __restrict__ B2,
                                                 const float* __restrict__ bl2,
                                                 const float* __restrict__ Wl3,
                                                 const float* __restrict__ bl3,
                                                 float* __restrict__ out) {
    __shared__ __align__(16) unsigned short h64s[64 * 72];  // stride 72 breaks bank aliasing
    __shared__ float hs[64][33];
    int tid = threadIdx.x;
    int lane = tid & 63;
    int wv = tid >> 6;
    int mt = blockIdx.x * 4 + wv;
    if (mt >= MT_TILES) mt = MT_TILES - 1;
    int q = lane >> 4;
    int rl = lane & 15;
    // stage 1: K=128 (4 kt), N=64 (4 nt); A built from fp32 emb on the fly
    const frag_ab* bp1 = (const frag_ab*)B1;
    frag_cd acc[4];
    #pragma unroll
    for (int nt = 0; nt < 4; nt++) acc[nt] = (frag_cd){0.f, 0.f, 0.f, 0.f};
    #pragma unroll
    for (int kt = 0; kt < 4; kt++) {
        const float4* ap = (const float4*)(emb + (mt * 16 + rl) * 128 + kt * 32 + q * 8);
        float4 f0 = ap[0], f1 = ap[1];
        frag_ab a;
        a[0] = (short)f2b(f0.x); a[1] = (short)f2b(f0.y);
        a[2] = (short)f2b(f0.z); a[3] = (short)f2b(f0.w);
        a[4] = (short)f2b(f1.x); a[5] = (short)f2b(f1.y);
        a[6] = (short)f2b(f1.z); a[7] = (short)f2b(f1.w);
        #pragma unroll
        for (int nt = 0; nt < 4; nt++)
            acc[nt] = __builtin_amdgcn_mfma_f32_16x16x32_bf16(a, bp1[(kt * 4 + nt) * 64 + lane], acc[nt], 0, 0, 0);
    }
    #pragma unroll
    for (int nt = 0; nt < 4; nt++) {
        int c = nt * 16 + rl;
        float bias = bl1[c];
        #pragma unroll
        for (int i = 0; i < 4; i++) {
            float v = acc[nt][i] + bias;
            h64s[(wv * 16 + q * 4 + i) * 72 + c] = f2b(v > 0.f ? v : 0.f);
        }
    }
    __syncthreads();
    // stage 2: K=64 (2 kt), N=32 (2 nt); A from LDS
    const unsigned short* a2 = h64s + (wv * 16 + rl) * 72 + q * 8;
    const frag_ab* bp2 = (const frag_ab*)B2;
    frag_cd acc2[2];
    #pragma unroll
    for (int nt = 0; nt < 2; nt++) acc2[nt] = (frag_cd){0.f, 0.f, 0.f, 0.f};
    #pragma unroll
    for (int kt = 0; kt < 2; kt++) {
        frag_ab a = *(const frag_ab*)(a2 + kt * 32);
        #pragma unroll
        for (int nt = 0; nt < 2; nt++)
            acc2[nt] = __builtin_amdgcn_mfma_f32_16x16x32_bf16(a, bp2[(kt * 2 + nt) * 64 + lane], acc2[nt], 0, 0, 0);
    }
    #pragma unroll
    for (int nt = 0; nt < 2; nt++) {
        int c = nt * 16 + rl;
        float bias = bl2[c];
        #pragma unroll
        for (int i = 0; i < 4; i++) {
            int lr = wv * 16 + q * 4 + i;
            float v = acc2[nt][i] + bias;
            hs[lr][c] = v > 0.f ? v : 0.f;
        }
    }
    __syncthreads();
    int base = blockIdx.x * 64;
    for (int idx = tid; idx < 640; idx += 256) {
        int lr = idx / 10;
        int j = idx - lr * 10;
        int n = base + lr;
        if (n < N_NODES) {
            float a = bl3[j];
            #pragma unroll
            for (int k = 0; k < 32; k++) a += hs[lr][k] * Wl3[k * 10 + j];
            out[n * 10 + j] = a;
        }
    }
}

// ---------------- launch ----------------

extern "C" void kernel_launch(void* const* d_in, const int* in_sizes, int n_in,
                              void* d_out, int out_size, void* d_ws, size_t ws_size,
                              hipStream_t stream) {
    const float* x   = (const float*)d_in[0];
    const int* esrc  = (const int*)d_in[1];
    const int* edst  = (const int*)d_in[2];
    const float* ew  = (const float*)d_in[3];
    const float* W1s = (const float*)d_in[4];
    const float* W1n = (const float*)d_in[5];
    const float* b1  = (const float*)d_in[6];
    const float* W2s = (const float*)d_in[7];
    const float* W2n = (const float*)d_in[8];
    const float* b2  = (const float*)d_in[9];
    const float* Wl1 = (const float*)d_in[10];
    const float* bl1 = (const float*)d_in[11];
    const float* Wl2 = (const float*)d_in[12];
    const float* bl2 = (const float*)d_in[13];
    const float* Wl3 = (const float*)d_in[14];
    const float* bl3 = (const float*)d_in[15];

    float* out = (float*)d_out;       // [50000,10]
    float* emb = out + 500000;        // [50000,128] output 1

    char* ws = (char*)d_ws;
    size_t off = 0;
    auto alloc = [&](size_t bytes) -> void* {
        void* p = ws + off;
        off = (off + bytes + 255) & ~(size_t)255;
        return p;
    };
    int*   row_off = (int*)alloc((size_t)(N_NODES + 1) * 4);
    float* inv_deg = (float*)alloc((size_t)N_NODES * 4);
    int*   G       = (int*)alloc((size_t)NBLK_SORT * 256 * 4);
    int*   colsum  = (int*)alloc(256 * 4);
    int*   bdst    = (int*)alloc((size_t)N_EDGES * 4);
    int2*  bsedge  = (int2*)alloc((size_t)N_EDGES * 8);
    int2*  sedge   = (int2*)alloc((size_t)N_EDGES * 8);
    unsigned short* xb   = (unsigned short*)alloc((size_t)N_NODES * 64 * 2);
    unsigned short* hn1b = (unsigned short*)alloc((size_t)N_NODES * 64 * 2);
    unsigned short* x1b  = (unsigned short*)alloc((size_t)N_NODES * 256 * 2);
    unsigned short* zb   = (unsigned short*)alloc((size_t)N_NODES * 128 * 2);
    unsigned short* B1p  = (unsigned short*)alloc(128 * 256 * 2);
    unsigned short* B2p  = (unsigned short*)alloc(256 * 256 * 2);
    unsigned short* Bl1p = (unsigned short*)alloc(128 * 64 * 2);
    unsigned short* Bl2p = (unsigned short*)alloc(64 * 32 * 2);

    // fused cvt + weight packing + p1 histogram
    prep_p1_kernel<<<PREP_BLKS + NBLK_SORT, 256, 0, stream>>>(
        (const float4*)x, (ushort4*)xb, W1s, W1n, W2s, W2n, Wl1, Wl2,
        B1p, B2p, Bl1p, Bl2p, edst, G);

    // parallel scans + scatter + per-bucket sort
    p2a_scan<<<256, 256, 0, stream>>>(G, colsum);
    p3_scatter<<<NBLK_SORT, 256, 0, stream>>>(esrc, edst, ew, G, colsum, bdst, bsedge);
    p4_sort<<<NBKT, 256, 0, stream>>>(colsum, bdst, bsedge, row_off, inv_deg, sedge);

    const int GBLK8 = (MT_TILES + 7) / 8;  // 391 (8 m-tiles/block, 512 threads)
    const int GBLK  = (MT_TILES + 3) / 4;  // 782
    const int ABLK  = (N_NODES + 3) / 4;   // 12500

    // layer 1
    agg64_kernel<<<ABLK, 256, 0, stream>>>((const uint4*)xb, row_off, sedge,
                                           inv_deg, (uint4*)hn1b);
    gemm1_mfma<<<GBLK8, 512, 0, stream>>>(xb, hn1b, B1p, b1, x1b);

    // layer 2: GEMM first (self + z), then aggregate z in 128-dim
    gemm2_mfma<<<GBLK8, 512, 0, stream>>>(x1b, B2p, b2, emb, zb);
    agg128_kernel<<<ABLK, 256, 0, stream>>>((const uint4*)zb, row_off, sedge,
                                            inv_deg, emb);

    // fused MLP head (reads fp32 emb, converts on the fly)
    mlp_fused<<<GBLK, 256, 0, stream>>>(emb, Bl1p, bl1, Bl2p, bl2, Wl3, bl3, out);
}

// Round 5
// 227.982 us; speedup vs baseline: 1.0602x; 1.0309x over previous
//
#include <hip/hip_runtime.h>
#include <hip/hip_bf16.h>

#define N_NODES 50000
#define N_EDGES 800000
#define MT_TILES 3125   // 50000 / 16

#define NBLK_SORT 400
#define CHUNK_SORT 2000   // NBLK_SORT * CHUNK_SORT == N_EDGES
#define NBKT 196          // ceil(50000 / 256)

typedef __attribute__((ext_vector_type(8))) short frag_ab;   // 8 bf16 (4 VGPRs)
typedef __attribute__((ext_vector_type(4))) float frag_cd;   // 4 fp32 acc

static __device__ __forceinline__ unsigned short f2b(float f) {
    union { float f; unsigned u; } v; v.f = f;
    unsigned r = v.u + 0x7fffu + ((v.u >> 16) & 1u);  // RNE
    return (unsigned short)(r >> 16);
}
static __device__ __forceinline__ float b2f(unsigned short b) {
    union { float f; unsigned u; } v; v.u = ((unsigned)b) << 16;
    return v.f;
}
static __device__ __forceinline__ float blo(unsigned p) { return b2f((unsigned short)(p & 0xffffu)); }
static __device__ __forceinline__ float bhi(unsigned p) { return b2f((unsigned short)(p >> 16)); }

// ---------------- fused prep (cvt x, pack weights) + p1 bucket histogram ----------------
static __device__ __forceinline__ unsigned short packBK_elem(const float* __restrict__ Wa,
                                                             const float* __restrict__ Wb,
                                                             int Ka, int N, int idx) {
    int j = idx & 7;
    int lane = (idx >> 3) & 63;
    int rest = idx >> 9;
    int ntiles = N >> 4;
    int nt = rest % ntiles;
    int kt = rest / ntiles;
    int kk = kt * 32 + (lane >> 4) * 8 + j;
    int nn = nt * 16 + (lane & 15);
    float v = (kk < Ka) ? Wa[kk * N + nn] : Wb[(kk - Ka) * N + nn];
    return f2b(v);
}
static __device__ __forceinline__ unsigned short packBN_elem(const float* __restrict__ Wa,
                                                             const float* __restrict__ Wb,
                                                             int Na, int N, int idx) {
    int j = idx & 7;
    int lane = (idx >> 3) & 63;
    int rest = idx >> 9;
    int ntiles = N >> 4;
    int nt = rest % ntiles;
    int kt = rest / ntiles;
    int kk = kt * 32 + (lane >> 4) * 8 + j;
    int nn = nt * 16 + (lane & 15);
    float v = (nn < Na) ? Wa[kk * Na + nn] : Wb[kk * (N - Na) + (nn - Na)];
    return f2b(v);
}

#define PREP_S0 800000                 // cvt: ushort4 items (N_NODES*64/4)
#define PREP_S1 (PREP_S0 + 32768)      // B1p  128x256
#define PREP_S2 (PREP_S1 + 65536)      // B2p  256x256
#define PREP_S3 (PREP_S2 + 8192)      // Bl1p 128x64
#define PREP_S4 (PREP_S3 + 2048)      // Bl2p 64x32   -> total 908544 = 3549*256
#define PREP_BLKS 3549

__global__ __launch_bounds__(256) void prep_p1_kernel(const float4* __restrict__ x4,
                                                      ushort4* __restrict__ xb4,
                                                      const float* __restrict__ W1s,
                                                      const float* __restrict__ W1n,
                                                      const float* __restrict__ W2s,
                                                      const float* __restrict__ W2n,
                                                      const float* __restrict__ Wl1,
                                                      const float* __restrict__ Wl2,
                                                      unsigned short* __restrict__ B1p,
                                                      unsigned short* __restrict__ B2p,
                                                      unsigned short* __restrict__ Bl1p,
                                                      unsigned short* __restrict__ Bl2p,
                                                      const int* __restrict__ dst,
                                                      int* __restrict__ G) {
    __shared__ int h[256];
    int bid = blockIdx.x;
    int t = threadIdx.x;
    if (bid >= PREP_BLKS) {
        // p1: per-block bucket histogram (bucket = dst >> 8)
        int blk = bid - PREP_BLKS;
        h[t] = 0;
        __syncthreads();
        int base = blk * CHUNK_SORT;
        for (int i = t; i < CHUNK_SORT; i += 256)
            atomicAdd(&h[dst[base + i] >> 8], 1);
        __syncthreads();
        G[blk * 256 + t] = h[t];
        return;
    }
    int idx = bid * 256 + t;
    if (idx < PREP_S0) {
        float4 v = x4[idx];
        ushort4 o;
        o.x = f2b(v.x); o.y = f2b(v.y); o.z = f2b(v.z); o.w = f2b(v.w);
        xb4[idx] = o;
    } else if (idx < PREP_S1) {
        int i = idx - PREP_S0;
        B1p[i] = packBK_elem(W1s, W1n, 64, 256, i);
    } else if (idx < PREP_S2) {
        int i = idx - PREP_S1;
        B2p[i] = packBN_elem(W2s, W2n, 128, 256, i);
    } else if (idx < PREP_S3) {
        int i = idx - PREP_S2;
        Bl1p[i] = packBK_elem(Wl1, Wl1, 128, 64, i);
    } else {
        int i = idx - PREP_S3;
        Bl2p[i] = packBK_elem(Wl2, Wl2, 64, 32, i);
    }
}

// ---------------- CSR build: parallel scans, no global atomics ----------------

// p2a: one block per bucket column b — scan G[0..NBLK-1][b] (pair-loaded, 2 per thread)
__global__ __launch_bounds__(256) void p2a_scan(int* __restrict__ G,
                                                int* __restrict__ colsum) {
    __shared__ int sc[256];
    int b = blockIdx.x;
    int t = threadIdx.x;
    int j0 = 2 * t, j1 = 2 * t + 1;
    int v0 = (j0 < NBLK_SORT) ? G[j0 * 256 + b] : 0;
    int v1 = (j1 < NBLK_SORT) ? G[j1 * 256 + b] : 0;
    int v = v0 + v1;
    sc[t] = v;
    __syncthreads();
    for (int off = 1; off < 256; off <<= 1) {
        int add = (t >= off) ? sc[t - off] : 0;
        __syncthreads();
        sc[t] += add;
        __syncthreads();
    }
    int ex = sc[t] - v;  // exclusive over pairs
    if (j0 < NBLK_SORT) G[j0 * 256 + b] = ex;
    if (j1 < NBLK_SORT) G[j1 * 256 + b] = ex + v0;
    if (t == 255) colsum[b] = sc[255];
}

// p3: scatter edges into bucket-grouped array via LDS cursors.
// Packs (dst_local<<16)|src into .x (src < 65536, dst_local < 256) — no bdst array.
__global__ __launch_bounds__(256) void p3_scatter(const int* __restrict__ src,
                                                  const int* __restrict__ dst,
                                                  const float* __restrict__ w,
                                                  const int* __restrict__ G,
                                                  const int* __restrict__ colsum,
                                                  int2* __restrict__ bsedge) {
    __shared__ int cur[256];
    __shared__ int sc[256];
    int t = threadIdx.x;
    int v = colsum[t];
    sc[t] = v;
    __syncthreads();
    for (int off = 1; off < 256; off <<= 1) {
        int add = (t >= off) ? sc[t - off] : 0;
        __syncthreads();
        sc[t] += add;
        __syncthreads();
    }
    cur[t] = G[blockIdx.x * 256 + t] + (sc[t] - v);  // block prefix + bucket offset
    __syncthreads();
    int base = blockIdx.x * CHUNK_SORT;
    for (int i = t; i < CHUNK_SORT; i += 256) {
        int e = base + i;
        int d = dst[e];
        int pos = atomicAdd(&cur[d >> 8], 1);
        bsedge[pos] = make_int2(((d & 255) << 16) | src[e], __float_as_int(w[e]));
    }
}

// p4: one block per bucket — LDS counting sort by dst_local, emit row_off/inv_deg/sedge
__global__ __launch_bounds__(256) void p4_sort(const int* __restrict__ colsum,
                                               const int2* __restrict__ bsedge,
                                               int* __restrict__ row_off,
                                               float* __restrict__ inv_deg,
                                               int2* __restrict__ sedge) {
    __shared__ int lcnt[256];
    __shared__ int lcur[256];
    __shared__ int sc[256];
    __shared__ int sE0, sE1;
    int t = threadIdx.x;
    int b = blockIdx.x;
    // recompute bucket offsets from colsum (inclusive scan)
    int cv = colsum[t];
    sc[t] = cv;
    __syncthreads();
    for (int off = 1; off < 256; off <<= 1) {
        int add = (t >= off) ? sc[t - off] : 0;
        __syncthreads();
        sc[t] += add;
        __syncthreads();
    }
    if (t == b) { sE0 = sc[t] - cv; sE1 = sc[t]; }
    lcnt[t] = 0;
    __syncthreads();
    int e0 = sE0, e1 = sE1;
    int d0 = b << 8;
    for (int e = e0 + t; e < e1; e += 256)
        atomicAdd(&lcnt[bsedge[e].x >> 16], 1);
    __syncthreads();
    int v = lcnt[t];
    sc[t] = v;
    __syncthreads();
    for (int off = 1; off < 256; off <<= 1) {
        int add = (t >= off) ? sc[t - off] : 0;
        __syncthreads();
        sc[t] += add;
        __syncthreads();
    }
    int loff = e0 + sc[t] - v;  // exclusive, global
    lcur[t] = loff;
    int d = d0 + t;
    if (d < N_NODES) {
        row_off[d] = loff;
        inv_deg[d] = 1.0f / (float)(v > 0 ? v : 1);
    }
    if (b == 0 && t == 0) row_off[N_NODES] = N_EDGES;
    __syncthreads();
    for (int e = e0 + t; e < e1; e += 256) {
        int2 pk = bsedge[e];
        int dl = pk.x >> 16;
        int pos = atomicAdd(&lcur[dl], 1);
        sedge[pos] = make_int2(pk.x & 0xffff, pk.y);
    }
}

// ---------------- Aggregations (gather; 4 waves/block, 1 node/wave) ----------------
// All edge slots in a 16-edge chunk are issued in parallel (clamped index +
// zeroed weight for out-of-range slots).

// d=64: eighth-wave per edge (8 lanes x dwordx4); 16 edges in flight per wave
__global__ __launch_bounds__(256) void agg64_kernel(const uint4* __restrict__ xb4,
                                                    const int* __restrict__ row_off,
                                                    const int2* __restrict__ sedge,
                                                    const float* __restrict__ inv_deg,
                                                    uint4* __restrict__ hn1b4) {
    int tid = threadIdx.x;
    int lane = tid & 63;
    int er = lane >> 3;   // edge slot 0..7
    int l7 = lane & 7;    // dim slot (8 bf16 each)
    int n = blockIdx.x * 4 + (tid >> 6);
    if (n >= N_NODES) return;
    int e0 = row_off[n], e1 = row_off[n + 1];
    float id = inv_deg[n];
    float a[8];
    #pragma unroll
    for (int j = 0; j < 8; j++) a[j] = 0.f;
    int e1m1 = e1 - 1;
    for (int e = e0; e < e1; e += 16) {
        int2 m[2];
        uint4 p[2];
        float w[2];
        #pragma unroll
        for (int k = 0; k < 2; k++) {
            int ee = e + k * 8 + er;
            int idx = ee < e1 ? ee : e1m1;
            m[k] = sedge[idx];
        }
        #pragma unroll
        for (int k = 0; k < 2; k++) {
            p[k] = xb4[m[k].x * 8 + l7];
            int ee = e + k * 8 + er;
            w[k] = (ee < e1) ? __int_as_float(m[k].y) : 0.f;
        }
        #pragma unroll
        for (int k = 0; k < 2; k++) {
            a[0] += w[k] * blo(p[k].x); a[1] += w[k] * bhi(p[k].x);
            a[2] += w[k] * blo(p[k].y); a[3] += w[k] * bhi(p[k].y);
            a[4] += w[k] * blo(p[k].z); a[5] += w[k] * bhi(p[k].z);
            a[6] += w[k] * blo(p[k].w); a[7] += w[k] * bhi(p[k].w);
        }
    }
    #pragma unroll
    for (int j = 0; j < 8; j++) {
        a[j] += __shfl_xor(a[j], 8, 64);
        a[j] += __shfl_xor(a[j], 16, 64);
        a[j] += __shfl_xor(a[j], 32, 64);
    }
    if (er == 0) {
        uint4 o;
        o.x = (unsigned)f2b(a[0] * id) | ((unsigned)f2b(a[1] * id) << 16);
        o.y = (unsigned)f2b(a[2] * id) | ((unsigned)f2b(a[3] * id) << 16);
        o.z = (unsigned)f2b(a[4] * id) | ((unsigned)f2b(a[5] * id) << 16);
        o.w = (unsigned)f2b(a[6] * id) | ((unsigned)f2b(a[7] * id) << 16);
        hn1b4[n * 8 + l7] = o;
    }
}

// d=128: quarter-wave per edge (16 lanes x dwordx4); writes bf16 hn only (no emb RMW)
__global__ __launch_bounds__(256) void agg128_kernel(const uint4* __restrict__ zb4,
                                                     const int* __restrict__ row_off,
                                                     const int2* __restrict__ sedge,
                                                     const float* __restrict__ inv_deg,
                                                     uint4* __restrict__ hnb4) {
    int tid = threadIdx.x;
    int lane = tid & 63;
    int qr = lane >> 4;   // edge slot 0..3
    int l15 = lane & 15;  // dim slot (8 bf16 each)
    int n = blockIdx.x * 4 + (tid >> 6);
    if (n >= N_NODES) return;
    int e0 = row_off[n], e1 = row_off[n + 1];
    float id = inv_deg[n];
    float a[8];
    #pragma unroll
    for (int j = 0; j < 8; j++) a[j] = 0.f;
    int e1m1 = e1 - 1;
    for (int e = e0; e < e1; e += 16) {
        int2 m[4];
        uint4 p[4];
        float w[4];
        #pragma unroll
        for (int k = 0; k < 4; k++) {
            int ee = e + k * 4 + qr;
            int idx = ee < e1 ? ee : e1m1;
            m[k] = sedge[idx];
        }
        #pragma unroll
        for (int k = 0; k < 4; k++) {
            p[k] = zb4[m[k].x * 16 + l15];
            int ee = e + k * 4 + qr;
            w[k] = (ee < e1) ? __int_as_float(m[k].y) : 0.f;
        }
        #pragma unroll
        for (int k = 0; k < 4; k++) {
            a[0] += w[k] * blo(p[k].x); a[1] += w[k] * bhi(p[k].x);
            a[2] += w[k] * blo(p[k].y); a[3] += w[k] * bhi(p[k].y);
            a[4] += w[k] * blo(p[k].z); a[5] += w[k] * bhi(p[k].z);
            a[6] += w[k] * blo(p[k].w); a[7] += w[k] * bhi(p[k].w);
        }
    }
    #pragma unroll
    for (int j = 0; j < 8; j++) {
        a[j] += __shfl_xor(a[j], 16, 64);
        a[j] += __shfl_xor(a[j], 32, 64);
    }
    if (qr == 0) {
        uint4 o;
        o.x = (unsigned)f2b(a[0] * id) | ((unsigned)f2b(a[1] * id) << 16);
        o.y = (unsigned)f2b(a[2] * id) | ((unsigned)f2b(a[3] * id) << 16);
        o.z = (unsigned)f2b(a[4] * id) | ((unsigned)f2b(a[5] * id) << 16);
        o.w = (unsigned)f2b(a[6] * id) | ((unsigned)f2b(a[7] * id) << 16);
        hnb4[n * 16 + l15] = o;
    }
}

// ---------------- MFMA GEMMs: 8 m-tiles/block (512 thr), double-buffered B staging ----------------

// x1b = bf16(relu([xb|hn1b] @ [W1s;W1n] + b1))   K=128 (4 kt), N=256
__global__ __launch_bounds__(512) void gemm1_mfma(const unsigned short* __restrict__ xb,
                                                  const unsigned short* __restrict__ hn1b,
                                                  const unsigned short* __restrict__ Bp,
                                                  const float* __restrict__ b1,
                                                  unsigned short* __restrict__ x1b) {
    __shared__ __align__(16) unsigned short sB[2][8192];
    int tid = threadIdx.x;
    int lane = tid & 63;
    int wv = tid >> 6;                 // 0..7
    int mt = blockIdx.x * 8 + wv;
    if (mt >= MT_TILES) mt = MT_TILES - 1;  // dup wave, benign same-value stores
    int q = lane >> 4;
    int rl = lane & 15;
    int row = mt * 16 + rl;
    frag_ab a[4];
    a[0] = *(const frag_ab*)(xb + row * 64 + q * 8);
    a[1] = *(const frag_ab*)(xb + row * 64 + q * 8 + 32);
    a[2] = *(const frag_ab*)(hn1b + row * 64 + q * 8);
    a[3] = *(const frag_ab*)(hn1b + row * 64 + q * 8 + 32);
    frag_cd acc[16];
    #pragma unroll
    for (int nt = 0; nt < 16; nt++) acc[nt] = (frag_cd){0.f, 0.f, 0.f, 0.f};
    const float4* gB = (const float4*)Bp;   // 1024 float4 per kt
    float4 s0 = gB[tid], s1 = gB[512 + tid];
    ((float4*)sB[0])[tid] = s0;
    ((float4*)sB[0])[512 + tid] = s1;
    #pragma unroll
    for (int kt = 0; kt < 4; kt++) {
        __syncthreads();
        if (kt < 3) { s0 = gB[(kt + 1) * 1024 + tid]; s1 = gB[(kt + 1) * 1024 + 512 + tid]; }
        const unsigned short* sb = sB[kt & 1];
        #pragma unroll
        for (int nt = 0; nt < 16; nt++) {
            frag_ab b = *(const frag_ab*)(sb + (nt * 64 + lane) * 8);
            acc[nt] = __builtin_amdgcn_mfma_f32_16x16x32_bf16(a[kt], b, acc[nt], 0, 0, 0);
        }
        if (kt < 3) {
            ((float4*)sB[(kt + 1) & 1])[tid] = s0;
            ((float4*)sB[(kt + 1) & 1])[512 + tid] = s1;
        }
    }
    int r0 = mt * 16;
    #pragma unroll
    for (int nt = 0; nt < 16; nt++) {
        int c = nt * 16 + rl;
        float bias = b1[c];
        #pragma unroll
        for (int i = 0; i < 4; i++) {
            int r = r0 + q * 4 + i;
            float v = acc[nt][i] + bias;
            v = v > 0.f ? v : 0.f;
            x1b[r * 256 + c] = f2b(v);
        }
    }
}

// self+z: x1b @ [W2s|W2n]; cols 0-127 -> embS fp32 (+b2), cols 128-255 -> zb bf16. K=256 (8 kt)
__global__ __launch_bounds__(512) void gemm2_mfma(const unsigned short* __restrict__ x1b,
                                                  const unsigned short* __restrict__ Bp,
                                                  const float* __restrict__ b2,
                                                  float* __restrict__ embS,
                                                  unsigned short* __restrict__ zb) {
    __shared__ __align__(16) unsigned short sB[2][8192];
    int tid = threadIdx.x;
    int lane = tid & 63;
    int wv = tid >> 6;
    int mt = blockIdx.x * 8 + wv;
    if (mt >= MT_TILES) mt = MT_TILES - 1;
    int q = lane >> 4;
    int rl = lane & 15;
    int row = mt * 16 + rl;
    const unsigned short* arow = x1b + row * 256 + q * 8;
    frag_ab a[8];
    #pragma unroll
    for (int kt = 0; kt < 8; kt++) a[kt] = *(const frag_ab*)(arow + kt * 32);
    frag_cd acc[16];
    #pragma unroll
    for (int nt = 0; nt < 16; nt++) acc[nt] = (frag_cd){0.f, 0.f, 0.f, 0.f};
    const float4* gB = (const float4*)Bp;
    float4 s0 = gB[tid], s1 = gB[512 + tid];
    ((float4*)sB[0])[tid] = s0;
    ((float4*)sB[0])[512 + tid] = s1;
    #pragma unroll
    for (int kt = 0; kt < 8; kt++) {
        __syncthreads();
        if (kt < 7) { s0 = gB[(kt + 1) * 1024 + tid]; s1 = gB[(kt + 1) * 1024 + 512 + tid]; }
        const unsigned short* sb = sB[kt & 1];
        #pragma unroll
        for (int nt = 0; nt < 16; nt++) {
            frag_ab b = *(const frag_ab*)(sb + (nt * 64 + lane) * 8);
            acc[nt] = __builtin_amdgcn_mfma_f32_16x16x32_bf16(a[kt], b, acc[nt], 0, 0, 0);
        }
        if (kt < 7) {
            ((float4*)sB[(kt + 1) & 1])[tid] = s0;
            ((float4*)sB[(kt + 1) & 1])[512 + tid] = s1;
        }
    }
    int r0 = mt * 16;
    #pragma unroll
    for (int nt = 0; nt < 8; nt++) {
        int c = nt * 16 + rl;
        float bias = b2[c];
        #pragma unroll
        for (int i = 0; i < 4; i++) {
            int r = r0 + q * 4 + i;
            embS[r * 128 + c] = acc[nt][i] + bias;
        }
    }
    #pragma unroll
    for (int nt = 8; nt < 16; nt++) {
        int c = (nt - 8) * 16 + rl;
        #pragma unroll
        for (int i = 0; i < 4; i++) {
            int r = r0 + q * 4 + i;
            zb[r * 128 + c] = f2b(acc[nt][i]);
        }
    }
}

// fused MLP head + emb finalize:
// sweep: emb = embS + hn (coalesced, fp32 out) staged as bf16 in LDS;
// h64 = relu(embA @ Wl1 + bl1); h32 = relu(h64 @ Wl2 + bl2); out = h32 @ Wl3 + bl3
__global__ __launch_bounds__(256) void mlp_fused(const float4* __restrict__ embS4,
                                                 const uint2* __restrict__ hnb2,
                                                 const unsigned short* __restrict__ B1,
                                                 const float* __restrict__ bl1,
                                                 const unsigned short* __restrict__ B2,
                                                 const float* __restrict__ bl2,
                                                 const float* __restrict__ Wl3,
                                                 const float* __restrict__ bl3,
                                                 float* __restrict__ out,
                                                 float4* __restrict__ emb4) {
    __shared__ __align__(16) unsigned short embA[64 * 136];  // 64 rows x 128 bf16, pad 8
    __shared__ __align__(16) unsigned short h64s[64 * 72];   // stride 72 breaks bank aliasing
    __shared__ float hs[64][33];
    int tid = threadIdx.x;
    int lane = tid & 63;
    int wv = tid >> 6;
    int base_n = blockIdx.x * 64;
    // finalize sweep: 64 rows x 32 float4-chunks = 2048 chunks, 8 per thread, coalesced
    #pragma unroll
    for (int it = 0; it < 8; it++) {
        int idx = it * 256 + tid;
        int r = idx >> 5;           // local row 0..63
        int c4 = idx & 31;          // float4 chunk within row (dims c4*4..c4*4+3)
        int n = base_n + r;
        if (n >= N_NODES) n = N_NODES - 1;   // dup, same-value stores benign
        float4 v = embS4[(size_t)n * 32 + c4];
        uint2 h = hnb2[(size_t)n * 32 + c4];
        v.x += blo(h.x); v.y += bhi(h.x);
        v.z += blo(h.y); v.w += bhi(h.y);
        emb4[(size_t)n * 32 + c4] = v;
        ushort4 o;
        o.x = f2b(v.x); o.y = f2b(v.y); o.z = f2b(v.z); o.w = f2b(v.w);
        *(ushort4*)(embA + r * 136 + c4 * 4) = o;
    }
    __syncthreads();
    int mt = blockIdx.x * 4 + wv;
    if (mt >= MT_TILES) mt = MT_TILES - 1;
    int q = lane >> 4;
    int rl = lane & 15;
    // stage 1: K=128 (4 kt), N=64 (4 nt); A from embA LDS
    const unsigned short* a1base = embA + (wv * 16 + rl) * 136 + q * 8;
    const frag_ab* bp1 = (const frag_ab*)B1;
    frag_cd acc[4];
    #pragma unroll
    for (int nt = 0; nt < 4; nt++) acc[nt] = (frag_cd){0.f, 0.f, 0.f, 0.f};
    #pragma unroll
    for (int kt = 0; kt < 4; kt++) {
        frag_ab a = *(const frag_ab*)(a1base + kt * 32);
        #pragma unroll
        for (int nt = 0; nt < 4; nt++)
            acc[nt] = __builtin_amdgcn_mfma_f32_16x16x32_bf16(a, bp1[(kt * 4 + nt) * 64 + lane], acc[nt], 0, 0, 0);
    }
    #pragma unroll
    for (int nt = 0; nt < 4; nt++) {
        int c = nt * 16 + rl;
        float bias = bl1[c];
        #pragma unroll
        for (int i = 0; i < 4; i++) {
            float v = acc[nt][i] + bias;
            h64s[(wv * 16 + q * 4 + i) * 72 + c] = f2b(v > 0.f ? v : 0.f);
        }
    }
    __syncthreads();
    // stage 2: K=64 (2 kt), N=32 (2 nt); A from LDS
    const unsigned short* a2 = h64s + (wv * 16 + rl) * 72 + q * 8;
    const frag_ab* bp2 = (const frag_ab*)B2;
    frag_cd acc2[2];
    #pragma unroll
    for (int nt = 0; nt < 2; nt++) acc2[nt] = (frag_cd){0.f, 0.f, 0.f, 0.f};
    #pragma unroll
    for (int kt = 0; kt < 2; kt++) {
        frag_ab a = *(const frag_ab*)(a2 + kt * 32);
        #pragma unroll
        for (int nt = 0; nt < 2; nt++)
            acc2[nt] = __builtin_amdgcn_mfma_f32_16x16x32_bf16(a, bp2[(kt * 2 + nt) * 64 + lane], acc2[nt], 0, 0, 0);
    }
    #pragma unroll
    for (int nt = 0; nt < 2; nt++) {
        int c = nt * 16 + rl;
        float bias = bl2[c];
        #pragma unroll
        for (int i = 0; i < 4; i++) {
            int lr = wv * 16 + q * 4 + i;
            float v = acc2[nt][i] + bias;
            hs[lr][c] = v > 0.f ? v : 0.f;
        }
    }
    __syncthreads();
    for (int idx = tid; idx < 640; idx += 256) {
        int lr = idx / 10;
        int j = idx - lr * 10;
        int n = base_n + lr;
        if (n < N_NODES) {
            float a = bl3[j];
            #pragma unroll
            for (int k = 0; k < 32; k++) a += hs[lr][k] * Wl3[k * 10 + j];
            out[n * 10 + j] = a;
        }
    }
}

// ---------------- launch ----------------

extern "C" void kernel_launch(void* const* d_in, const int* in_sizes, int n_in,
                              void* d_out, int out_size, void* d_ws, size_t ws_size,
                              hipStream_t stream) {
    const float* x   = (const float*)d_in[0];
    const int* esrc  = (const int*)d_in[1];
    const int* edst  = (const int*)d_in[2];
    const float* ew  = (const float*)d_in[3];
    const float* W1s = (const float*)d_in[4];
    const float* W1n = (const float*)d_in[5];
    const float* b1  = (const float*)d_in[6];
    const float* W2s = (const float*)d_in[7];
    const float* W2n = (const float*)d_in[8];
    const float* b2  = (const float*)d_in[9];
    const float* Wl1 = (const float*)d_in[10];
    const float* bl1 = (const float*)d_in[11];
    const float* Wl2 = (const float*)d_in[12];
    const float* bl2 = (const float*)d_in[13];
    const float* Wl3 = (const float*)d_in[14];
    const float* bl3 = (const float*)d_in[15];

    float* out = (float*)d_out;       // [50000,10]
    float* emb = out + 500000;        // [50000,128] output 1

    char* ws = (char*)d_ws;
    size_t off = 0;
    auto alloc = [&](size_t bytes) -> void* {
        void* p = ws + off;
        off = (off + bytes + 255) & ~(size_t)255;
        return p;
    };
    int*   row_off = (int*)alloc((size_t)(N_NODES + 1) * 4);
    float* inv_deg = (float*)alloc((size_t)N_NODES * 4);
    int*   G       = (int*)alloc((size_t)NBLK_SORT * 256 * 4);
    int*   colsum  = (int*)alloc(256 * 4);
    int2*  bsedge  = (int2*)alloc((size_t)N_EDGES * 8);
    int2*  sedge   = (int2*)alloc((size_t)N_EDGES * 8);
    unsigned short* xb   = (unsigned short*)alloc((size_t)N_NODES * 64 * 2);
    unsigned short* hn1b = (unsigned short*)alloc((size_t)N_NODES * 64 * 2);
    unsigned short* x1b  = (unsigned short*)alloc((size_t)N_NODES * 256 * 2);
    unsigned short* zb   = (unsigned short*)alloc((size_t)N_NODES * 128 * 2);
    unsigned short* hnb  = (unsigned short*)alloc((size_t)N_NODES * 128 * 2);
    float* embS          = (float*)alloc((size_t)N_NODES * 128 * 4);
    unsigned short* B1p  = (unsigned short*)alloc(128 * 256 * 2);
    unsigned short* B2p  = (unsigned short*)alloc(256 * 256 * 2);
    unsigned short* Bl1p = (unsigned short*)alloc(128 * 64 * 2);
    unsigned short* Bl2p = (unsigned short*)alloc(64 * 32 * 2);

    // fused cvt + weight packing + p1 histogram
    prep_p1_kernel<<<PREP_BLKS + NBLK_SORT, 256, 0, stream>>>(
        (const float4*)x, (ushort4*)xb, W1s, W1n, W2s, W2n, Wl1, Wl2,
        B1p, B2p, Bl1p, Bl2p, edst, G);

    // parallel scans + scatter + per-bucket sort
    p2a_scan<<<256, 256, 0, stream>>>(G, colsum);
    p3_scatter<<<NBLK_SORT, 256, 0, stream>>>(esrc, edst, ew, G, colsum, bsedge);
    p4_sort<<<NBKT, 256, 0, stream>>>(colsum, bsedge, row_off, inv_deg, sedge);

    const int GBLK8 = (MT_TILES + 7) / 8;  // 391 (8 m-tiles/block, 512 threads)
    const int GBLK  = (MT_TILES + 3) / 4;  // 782
    const int ABLK  = (N_NODES + 3) / 4;   // 12500

    // layer 1
    agg64_kernel<<<ABLK, 256, 0, stream>>>((const uint4*)xb, row_off, sedge,
                                           inv_deg, (uint4*)hn1b);
    gemm1_mfma<<<GBLK8, 512, 0, stream>>>(xb, hn1b, B1p, b1, x1b);

    // layer 2: GEMM (self -> embS, z -> zb), then aggregate z (bf16 hn only)
    gemm2_mfma<<<GBLK8, 512, 0, stream>>>(x1b, B2p, b2, embS, zb);
    agg128_kernel<<<ABLK, 256, 0, stream>>>((const uint4*)zb, row_off, sedge,
                                            inv_deg, (uint4*)hnb);

    // fused MLP head + emb finalize (emb = embS + hn, written here)
    mlp_fused<<<GBLK, 256, 0, stream>>>((const float4*)embS, (const uint2*)hnb,
                                        Bl1p, bl1, Bl2p, bl2, Wl3, bl3, out,
                                        (float4*)emb);
}